// Round 9
// baseline (501.482 us; speedup 1.0000x reference)
//
#include <hip/hip_runtime.h>

// CRF log-likelihood. B=256, L=1024, D=126, T=128. One block/batch, 512 thr.
// R12 = R11 (champion, 817 cyc/step) final diet:
//  1. DISTRIBUTED multi-reduce: merge the 4 accumulators during the
//     16-lane reduction (xor1-sel, xor2-sel, ror4, ror8) so group g's
//     total lands directly in lanes o&3==g -- kills the post-ring select
//     and one stage (14 instr vs 18).
//  2. Pointer-increment logit prefetch (uniform cselect advance) instead
//     of per-step mul+clamp addressing.
//  3. Write-early/barrier-late: E-write right after reduce; exp2 + global
//     prefetch + bookkeeping sit between write and lgkmcnt(0) as drain
//     cover.
// Everything else from R11: 8 waves (2/SIMD -- only quadrant that hides
// the ~550cyc stall core), thread = matvec partial for 4 outputs x 8
// inputs as 2 pk_fma chains, sig-permuted E (structural-2-way broadcast
// reads, measured-free), rebase every 4th step (exact pow2), 4-deep
// static prefetch ring, raw lgkmcnt(0)+s_barrier (vmcnt rides across).

typedef float v2f __attribute__((ext_vector_type(2)));

#define NEGV  (-10000.0f)
#define LOG2E 1.4426950408889634f
#define LN2   0.6931471805599453f

constexpr int Bc = 256, Lc = 1024, Dc = 126, Tc = 128;
constexpr int EP = Tc + 4;              // padded E row

#if __has_builtin(__builtin_amdgcn_exp2f)
#define FEXP2(x) __builtin_amdgcn_exp2f(x)
#else
#define FEXP2(x) exp2f(x)
#endif
#if __has_builtin(__builtin_amdgcn_logf)
#define FLOG2(x) __builtin_amdgcn_logf(x)
#else
#define FLOG2(x) log2f(x)
#endif

#if __has_builtin(__builtin_elementwise_fma)
#define PKFMA(a, b, c) __builtin_elementwise_fma((a), (b), (c))
#else
__device__ __forceinline__ v2f PKFMA(v2f a, v2f b, v2f c) {
    v2f r; r.x = fmaf(a.x, b.x, c.x); r.y = fmaf(a.y, b.y, c.y); return r;
}
#endif

// DPP: quad_perm xor1 (0xB1), xor2 (0x4E); row_ror:4/8 (0x124/0x128) ring
// ops on 16-lane rows. All validated in R5-R8.
#if __has_builtin(__builtin_amdgcn_mov_dpp)
#define DPPF(x, ctrl) __int_as_float(__builtin_amdgcn_mov_dpp(__float_as_int(x), (ctrl), 0xF, 0xF, true))
#define QX1(x)  DPPF(x, 0xB1)
#define QX2(x)  DPPF(x, 0x4E)
#define ROR1(x) DPPF(x, 0x121)
#define ROR2(x) DPPF(x, 0x122)
#define ROR4(x) DPPF(x, 0x124)
#define ROR8(x) DPPF(x, 0x128)
#else
#define QX1(x)  __shfl_xor((x), 1, 64)
#define QX2(x)  __shfl_xor((x), 2, 64)
#define ROR1(x) __shfl_xor((x), 1, 64)
#define ROR2(x) __shfl_xor((x), 2, 64)
#define ROR4(x) __shfl_xor((x), 4, 64)
#define ROR8(x) __shfl_xor((x), 8, 64)
#endif

#define STEP_BARRIER() asm volatile("s_waitcnt lgkmcnt(0)\n\ts_barrier" ::: "memory")

__device__ __forceinline__ int SIG(int q) { return q ^ (q >> 3); }   // bijective on [0,32)
__device__ __forceinline__ int Fmap(int k) { return 4 * SIG(k >> 2) + (k & 3); }

__global__ __launch_bounds__(512, 1) void crf_fwd_kernel(
    const float* __restrict__ x,      // [B, L, D]
    const float* __restrict__ trans,  // [T, T] row-major
    const int*   __restrict__ x_len,  // [B]
    const int*   __restrict__ tag,    // [B, L]
    float*       __restrict__ out)    // [B]
{
    __shared__ __align__(16) float E[2][EP];   // rebased exp(alpha), dbuf, sig-permuted
    __shared__ float red[12];                  // epilogue reductions

    const int b   = blockIdx.x;
    const int tid = threadIdx.x;
    const int w   = tid >> 6;             // wave 0..7
    const int l6  = tid & 63;
    const int o   = l6 & 15;              // k-octet: k in [8o, 8o+8)
    const int jg  = (w << 2) | (l6 >> 4); // j-group 0..31: j in [4jg, 4jg+4)
    const int len = x_len[b];             // block-uniform
    const int lenm1 = len - 1;

    const float* xb = x   + (size_t)b * Lc * Dc;
    const int*   tb = tag + (size_t)b * Lc;

    const int  f0 = 4 * SIG(2 * o);       // E read: k = 8o..8o+3
    const int  f1 = 4 * SIG(2 * o + 1);   //         k = 8o+4..8o+7
    const int  jown = 4 * jg + (o & 3);   // this thread's output state
    const bool jvalid = jown < Dc;        // j=126,127 are virtual NEG-pad
    const int  jr   = jvalid ? jown : 0;  // clamped load index
    const int  widx = 4 * SIG(jg) + (o & 3);  // own write slot (lanes o<4)

    // ---- constant weights, packed for pk_fma:
    // tP01[c] = {expT[4jg+0][8o+c], expT[4jg+1][8o+c]}, tP23 likewise ----
    v2f tP01[8], tP23[8];
    {
        const float4* t0p = reinterpret_cast<const float4*>(trans + (4*jg + 0) * Tc + 8*o);
        const float4* t1p = reinterpret_cast<const float4*>(trans + (4*jg + 1) * Tc + 8*o);
        const float4* t2p = reinterpret_cast<const float4*>(trans + (4*jg + 2) * Tc + 8*o);
        const float4* t3p = reinterpret_cast<const float4*>(trans + (4*jg + 3) * Tc + 8*o);
#pragma unroll
        for (int h = 0; h < 2; ++h) {
            float4 a = t0p[h], c = t1p[h], d = t2p[h], e = t3p[h];
            tP01[4*h+0] = (v2f){FEXP2(a.x*LOG2E), FEXP2(c.x*LOG2E)};
            tP01[4*h+1] = (v2f){FEXP2(a.y*LOG2E), FEXP2(c.y*LOG2E)};
            tP01[4*h+2] = (v2f){FEXP2(a.z*LOG2E), FEXP2(c.z*LOG2E)};
            tP01[4*h+3] = (v2f){FEXP2(a.w*LOG2E), FEXP2(c.w*LOG2E)};
            tP23[4*h+0] = (v2f){FEXP2(d.x*LOG2E), FEXP2(e.x*LOG2E)};
            tP23[4*h+1] = (v2f){FEXP2(d.y*LOG2E), FEXP2(e.y*LOG2E)};
            tP23[4*h+2] = (v2f){FEXP2(d.z*LOG2E), FEXP2(e.z*LOG2E)};
            tP23[4*h+3] = (v2f){FEXP2(d.w*LOG2E), FEXP2(e.w*LOG2E)};
        }
    }

    // ---- init E = delta(START=126) ----
    if (tid < Tc) E[0][Fmap(tid)] = (tid == Tc - 2) ? 1.0f : 0.0f;
    __syncthreads();

    // clamped load (prologue only)
#define LOADL(LS, DST) {                                        \
        int _s = (LS); if (_s > lenm1) _s = lenm1;              \
        float _v = xb[(size_t)_s * Dc + jr];                    \
        DST = jvalid ? _v : NEGV; }

    float P;                               // own emission factor, current step
    { float l0; LOADL(0, l0); P = FEXP2(l0 * LOG2E); }   // exp2(NEG*..) = 0
    float q0 = 0.f, q1, q2, q3;            // 4-deep prefetch ring (static idx)
    LOADL(1, q1); LOADL(2, q2); LOADL(3, q3);

    // increment-mode prefetch pointer: next row to load is min(4, lenm1)
    int prow = (4 <= lenm1) ? 4 : lenm1;
    const float* pl = xb + (size_t)prow * Dc + jr;

    int Mint = 0;                          // exact base-2 shift accumulator
    const int len4 = (len + 3) & ~3;

    // ---- forward recursion: one raw 8-wave barrier per step ----
#define BODY(C, QL, QN) {                                                       \
        const int  l   = l4 + (C);                                              \
        const bool act = l < len;         /* block-uniform tail guard */        \
        const int  p   = (C) & 1;                                               \
        const float* Ep = E[p];                                                 \
        float4 ea = *reinterpret_cast<const float4*>(Ep + f0);                  \
        float4 eb = *reinterpret_cast<const float4*>(Ep + f1);                  \
        v2f ee, acc01, acc23;                                                   \
        ee = (v2f){ea.x, ea.x}; acc01 = tP01[0] * ee; acc23 = tP23[0] * ee;     \
        ee = (v2f){ea.y, ea.y}; acc01 = PKFMA(tP01[1], ee, acc01);              \
                                acc23 = PKFMA(tP23[1], ee, acc23);              \
        ee = (v2f){ea.z, ea.z}; acc01 = PKFMA(tP01[2], ee, acc01);              \
                                acc23 = PKFMA(tP23[2], ee, acc23);              \
        ee = (v2f){ea.w, ea.w}; acc01 = PKFMA(tP01[3], ee, acc01);              \
                                acc23 = PKFMA(tP23[3], ee, acc23);              \
        ee = (v2f){eb.x, eb.x}; acc01 = PKFMA(tP01[4], ee, acc01);              \
                                acc23 = PKFMA(tP23[4], ee, acc23);              \
        ee = (v2f){eb.y, eb.y}; acc01 = PKFMA(tP01[5], ee, acc01);              \
                                acc23 = PKFMA(tP23[5], ee, acc23);              \
        ee = (v2f){eb.z, eb.z}; acc01 = PKFMA(tP01[6], ee, acc01);              \
                                acc23 = PKFMA(tP23[6], ee, acc23);              \
        ee = (v2f){eb.w, eb.w}; acc01 = PKFMA(tP01[7], ee, acc01);              \
                                acc23 = PKFMA(tP23[7], ee, acc23);              \
        float a0 = acc01.x, a1 = acc01.y, a2 = acc23.x, a3 = acc23.y;           \
        /* distributed multi-reduce: total for group g lands in lanes o&3==g */ \
        float sA = (o & 1) ? a0 : a1;     /* send */                            \
        float kA = (o & 1) ? a1 : a0;     /* keep */                            \
        float u0 = kA + QX1(sA);          /* pair-sum of group o&1 */           \
        float sB = (o & 1) ? a2 : a3;                                           \
        float kB = (o & 1) ? a3 : a2;                                           \
        float u1 = kB + QX1(sB);          /* pair-sum of group 2+(o&1) */       \
        float sC = (o & 2) ? u0 : u1;                                           \
        float kC = (o & 2) ? u1 : u0;                                           \
        float q  = kC + QX2(sC);          /* quad-sum of group o&3 */           \
        q += ROR4(q);                                                           \
        q += ROR8(q);                     /* full sum of group o&3 */           \
        float R = 1.0f;                                                         \
        if ((C) == 3 && act) {            /* rebase: exact pow2, k=2 mod 4 */   \
            float mx = fmaxf(ea.z, eb.z);                                       \
            mx = fmaxf(mx, ROR1(mx)); mx = fmaxf(mx, ROR2(mx));                 \
            mx = fmaxf(mx, ROR4(mx)); mx = fmaxf(mx, ROR8(mx));                 \
            int ebq = (__float_as_int(mx) >> 23) & 0xFF;                        \
            R = __int_as_float((254 - ebq) << 23);                              \
            Mint += ebq - 127;                                                  \
        }                                                                       \
        /* write EARLY; the ops below cover the lgkmcnt drain */                \
        if (act && o < 4) E[p ^ 1][widx] = q * P * R;                           \
        P = FEXP2(QN * LOG2E);            /* own emission for step l+1 */       \
        {                                 /* prefetch row prow (= l+4 clmp) */  \
            float _v = *pl;                                                     \
            QL = jvalid ? _v : NEGV;                                            \
            bool _adv = prow < lenm1;     /* uniform advance-or-hold */         \
            pl += _adv ? Dc : 0;                                                \
            prow += _adv ? 1 : 0;                                               \
        }                                                                       \
        STEP_BARRIER();                                                         \
    }

    for (int l4 = 0; l4 < len4; l4 += 4) {
        BODY(0, q0, q1)
        BODY(1, q1, q2)
        BODY(2, q2, q3)
        BODY(3, q3, q0)
    }
#undef BODY
#undef LOADL
    const int pf = len & 1;               // final E buffer

    // ---- score: emission + pairwise transitions (cooperative over l) ----
    float acc = 0.f;
    for (int l = tid; l < len; l += 512) {
        int   tg = tb[l];
        float tr = (l == 0) ? trans[tg * Tc + (Tc - 2)]
                            : trans[tg * Tc + tb[l - 1]];
        acc += xb[(size_t)l * Dc + tg] + tr;
    }
#pragma unroll
    for (int off = 1; off < 64; off <<= 1)
        acc += __shfl_xor(acc, off, 64);
    if (l6 == 0) red[w] = acc;

    // ---- partition = ln2 * (Mint + log2(sum_k exp(t_stop_k) * E_k)) ----
    if (w == 0) {
        int k0i = l6, k1i = 64 + l6;
        float p0 = FEXP2(trans[(Tc-1) * Tc + k0i] * LOG2E) * E[pf][Fmap(k0i)];
        float p1 = FEXP2(trans[(Tc-1) * Tc + k1i] * LOG2E) * E[pf][Fmap(k1i)];
        float ps = p0 + p1;
#pragma unroll
        for (int off = 1; off < 64; off <<= 1)
            ps += __shfl_xor(ps, off, 64);
        if (l6 == 0) red[8] = LN2 * ((float)Mint + FLOG2(ps));
    }
    __syncthreads();

    if (tid == 0) {
        float sc = trans[(Tc-1) * Tc + tb[len - 1]];   // STOP transition
#pragma unroll
        for (int i = 0; i < 8; ++i) sc += red[i];
        out[b] = sc - red[8];
    }
}

extern "C" void kernel_launch(void* const* d_in, const int* in_sizes, int n_in,
                              void* d_out, int out_size, void* d_ws, size_t ws_size,
                              hipStream_t stream) {
    const float* x     = (const float*)d_in[0];
    const float* trans = (const float*)d_in[1];
    // d_in[2] = x_mask (redundant with x_len)
    const int*   x_len = (const int*)d_in[3];
    const int*   tag   = (const int*)d_in[4];
    float*       out   = (float*)d_out;

    crf_fwd_kernel<<<Bc, 512, 0, stream>>>(x, trans, x_len, tag, out);
}